// Round 5
// baseline (5867.166 us; speedup 1.0000x reference)
//
#include <hip/hip_runtime.h>

// ---------------- problem constants ----------------
// S=512 seq, B=64 batch, I=256 in, H=1024 hidden, 4H=4096 gates
// Wx = [W1 W3 W5 W7] (input side), Wh = [W2 W4 W6 W8] (hidden side)
// out: h_seq (512,64,1024) fp32, then h_final (64,1024), c_final (64,1024)

// ---------------- workspace layout (bytes) ----------------
#define OFF_XB    0ul          // bf16 x      [512][64][256]   = 16 MiB
#define OFF_WXP   16777216ul   // bf16 Wx^T   [4096][256]      =  2 MiB (packed [col][k])
#define OFF_WHP   18874368ul   // bf16 Wh^T   [4096][1024]     =  8 MiB (packed [col][k], PRE-SWIZZLED)
#define OFF_BIAS  27262976ul   // f32 bx+bh   [4096]
#define OFF_HBUF  27279360ul   // u32 tagged h {bf16<<16|tag} [2][64][1024] = 512 KiB

typedef __attribute__((ext_vector_type(8))) __bf16 bf16x8;
typedef __attribute__((ext_vector_type(4))) float  floatx4;

struct KPtrs { const float* p[17]; };

__device__ __forceinline__ unsigned short f2bf(float f) {  // fp32 -> bf16 RTN-even
  unsigned int u = __float_as_uint(f);
  u += 0x7fffu + ((u >> 16) & 1u);
  return (unsigned short)(u >> 16);
}

__device__ __forceinline__ bf16x8 ld16(const unsigned short* p) {
  return *(const bf16x8*)p;   // cached global_load_dwordx4
}

__device__ __forceinline__ float fsig(float x) {
  return __builtin_amdgcn_rcpf(1.f + __expf(-x));
}
__device__ __forceinline__ float ftanh(float x) {
  return 1.f - 2.f * __builtin_amdgcn_rcpf(1.f + __expf(2.f * x));
}

// L3-coherent (agent-scope, L2-bypassing) relaxed 8B atomic load
__device__ __forceinline__ unsigned long long lduc64(const unsigned int* p) {
  return __hip_atomic_load((const unsigned long long*)p,
                           __ATOMIC_RELAXED, __HIP_MEMORY_SCOPE_AGENT);
}

// strip tags: 4 u64 (8 tagged u32, h in high 16 bits) -> 8 packed bf16
__device__ __forceinline__ bf16x8 unpack4(const unsigned long long* v) {
  unsigned int w[4];
#pragma unroll
  for (int i = 0; i < 4; ++i) {
    unsigned int lo = (unsigned int)v[i];
    unsigned int hi = (unsigned int)(v[i] >> 32);
    w[i] = __builtin_amdgcn_perm(hi, lo, 0x07060302);  // {hi.hi16, lo.hi16}
  }
  bf16x8 r;
  __builtin_memcpy(&r, w, 16);
  return r;
}

// ---------------- pack/convert + state init ----------------
__global__ void pack_kernel(KPtrs P, unsigned char* ws) {
  unsigned short* xb   = (unsigned short*)(ws + OFF_XB);
  unsigned short* wxp  = (unsigned short*)(ws + OFF_WXP);
  unsigned short* whp  = (unsigned short*)(ws + OFF_WHP);
  float*          bias = (float*)(ws + OFF_BIAS);
  unsigned int*   hb32 = (unsigned int*)(ws + OFF_HBUF);
  const float* x = P.p[0];

  const long tid = (long)blockIdx.x * blockDim.x + threadIdx.x;
  const long nth = (long)gridDim.x * blockDim.x;

  for (long e = tid; e < 8388608l; e += nth)       // x -> bf16, same flat layout
    xb[e] = f2bf(x[e]);
  for (long e = tid; e < 1048576l; e += nth) {     // Wx packed [col][k]
    int c = (int)(e >> 8), i = (int)(e & 255);
    int gg = c >> 10, j = c & 1023;
    wxp[e] = f2bf(P.p[1 + 4 * gg][i * 1024 + j]);  // W1,W3,W5,W7
  }
  // Wh packed [col][k], PRE-SWIZZLED: element (c,k) stored at k ^ ((c&7)<<3)
  // so LDS staging is a plain linear copy and ds_read_b128 with the same XOR
  // on the read side is bank-balanced. (Verified correct in R3/R4.)
  for (long e = tid; e < 4194304l; e += nth) {
    int c = (int)(e >> 10), k = (int)(e & 1023);
    int gg = c >> 10, j = c & 1023;
    long dst = ((long)c << 10) | (long)(k ^ ((c & 7) << 3));
    whp[dst] = f2bf(P.p[3 + 4 * gg][k * 1024 + j]);  // W2,W4,W6,W8
  }
  for (long e = tid; e < 4096l; e += nth) {        // bx + bh
    int gg = (int)(e >> 10), j = (int)(e & 1023);
    bias[e] = P.p[2 + 4 * gg][j] + P.p[4 + 4 * gg][j];
  }
  // tagged h double buffer = 0  (h=0, tag=0 == "h_{-1} ready"; UC stores -> L3)
  for (long e = tid; e < 131072l; e += nth)
    __hip_atomic_store(&hb32[e], 0u, __ATOMIC_RELAXED, __HIP_MEMORY_SCOPE_AGENT);
}

// issue / re-issue the full 64-u64 tagged h burst (all loads in flight at once)
#define H_BURST()                                              \
  do {                                                         \
    _Pragma("unroll")                                          \
    for (int kk2 = 0; kk2 < 8; ++kk2) {                        \
      _Pragma("unroll")                                        \
      for (int i2 = 0; i2 < 4; ++i2) {                         \
        hv[kk2 * 4 + i2]      = lduc64(hb0 + kk2 * 32 + 2 * i2); \
        hv[32 + kk2 * 4 + i2] = lduc64(hb1 + kk2 * 32 + 2 * i2); \
      }                                                        \
    }                                                          \
  } while (0)

// fold ALL 64 tag fields into one residual; forces every burst value live
// (single vmcnt batch -> one L3 round trip) before the first use.
#define H_CHECK()                                              \
  do {                                                         \
    d = 0;                                                     \
    _Pragma("unroll")                                          \
    for (int j2 = 0; j2 < 64; ++j2) d |= hv[j2] ^ tt;          \
    d &= TM;                                                   \
  } while (0)

// ---------------- persistent fused LSTM ----------------
// 128 blocks (proven co-resident) = 2 batch-groups (32 batches) x 64
// hidden-slices (16 units x 4 gates), 4 waves K-split.
//
// Exchange protocol (NO flags, NO fences, NO ack): h element = u32
// {bf16<<16 | (t+1)}, depth-2 parity buffer. Consumer tag-checks the exact
// words it feeds to MFMA. Safety: (a) a block's publish value is
// data-dependent on its h-reads, so reads are complete (served by L3) before
// the publish exists; (b) the pc-reduce barrier orders ALL waves' reads
// before ANY wave's publish; (c) a producer reaches its overwriting publish
// (same parity slot, 2 steps later) only after observing tags proving every
// reader published, hence finished reading. Lag >=2 steps is impossible, so
// a consumer never sees a too-new tag.
//
// Barrier discipline (R4 lesson: each store-draining barrier ~900 cy):
// exactly 2 barriers/step; sync1 drains only step-(t-1) stores (~2k cy old,
// free); sync2 sits BEFORE publish so it drains nothing.
__global__ void __launch_bounds__(256, 1)
lstm_kernel(const unsigned char* __restrict__ ws, float* __restrict__ out) {
  const unsigned short* xb   = (const unsigned short*)(ws + OFF_XB);
  const unsigned short* wxp  = (const unsigned short*)(ws + OFF_WXP);
  const unsigned short* whp  = (const unsigned short*)(ws + OFF_WHP);
  const float*          bias = (const float*)(ws + OFF_BIAS);
  unsigned int*         hbuf = (unsigned int*)(ws + OFF_HBUF);

  const int tid = threadIdx.x;
  const int wv = tid >> 6, lane = tid & 63;
  const int r = lane & 15, q = lane >> 4;          // MFMA frag row + k-quad
  const int s = blockIdx.x & 63, g = blockIdx.x >> 6;

  __shared__ unsigned short whl[65536];            // 128 KiB swizzled Wh slice
  __shared__ float pc[4][8][64][4];                // 32 KiB cross-wave reduce
                                                   // total 160 KiB (CU max)

  // ---- stage Wh slice into LDS (linear copy; swizzle pre-baked in whp) ----
  for (int ch = tid; ch < 8192; ch += 256) {
    const int le = ch * 8;                         // bf16 element index in whl
    const int rl = le >> 10, k8 = le & 1023;       // local row 0..63
    const int cg = (rl >> 4) * 1024 + s * 16 + (rl & 15);   // global gate col
    *(bf16x8*)&whl[le] = ld16(whp + (long)cg * 1024 + k8);
  }

  // ---- Wx fragments in registers (loop-invariant, 32 VGPR) ----
  bf16x8 wxf[4][2];
#pragma unroll
  for (int nt = 0; nt < 4; ++nt) {
    const int c = nt * 1024 + s * 16 + r;
#pragma unroll
    for (int kk = 0; kk < 2; ++kk)
      wxf[nt][kk] = ld16(wxp + (long)c * 256 + wv * 64 + kk * 32 + q * 8);
  }

  // epilogue mapping: thread -> (batches eb, eb+16 ; hidden col ej)
  const int ej = tid & 15, eb = tid >> 4;
  const int lidx = ej | ((eb >> 2) << 4), rg = eb & 3;   // C-frag coords
  float bs[4];
#pragma unroll
  for (int gt = 0; gt < 4; ++gt) bs[gt] = bias[gt * 1024 + s * 16 + ej];

  const unsigned short* xa0 = xb + (long)(g * 32 + r) * 256 + q * 8;
  const int hrow = (g * 32 + r) * 1024 + wv * 256 + q * 8;   // u32 index
  const int rs = (r & 7) << 3;                     // LDS XOR swizzle term
  const unsigned long long TM = 0x0000FFFF0000FFFFull;

  float cst[2] = {0.f, 0.f};
  __syncthreads();                                 // whl staged

  for (int t = 0; t < 512; ++t) {
    const unsigned long long tg = (unsigned int)t;
    const unsigned long long tt = tg | (tg << 32);

    // ---- x loads + x-side K (independent of peers) ----
    const unsigned short* xaT = xa0 + (long)t * 16384;
    bf16x8 xv[2][2];
#pragma unroll
    for (int kk = 0; kk < 2; ++kk) {
      xv[0][kk] = ld16(xaT + wv * 64 + kk * 32);
      xv[1][kk] = ld16(xaT + 16 * 256 + wv * 64 + kk * 32);
    }

    floatx4 acc[2][4];
#pragma unroll
    for (int mt = 0; mt < 2; ++mt)
#pragma unroll
      for (int nt = 0; nt < 4; ++nt) acc[mt][nt] = (floatx4){0.f, 0.f, 0.f, 0.f};

#pragma unroll
    for (int kk = 0; kk < 2; ++kk)
#pragma unroll
      for (int nt = 0; nt < 4; ++nt) {
        acc[0][nt] = __builtin_amdgcn_mfma_f32_16x16x32_bf16(xv[0][kk], wxf[nt][kk], acc[0][nt], 0, 0, 0);
        acc[1][nt] = __builtin_amdgcn_mfma_f32_16x16x32_bf16(xv[1][kk], wxf[nt][kk], acc[1][nt], 0, 0, 0);
      }

    // ---- tagged h burst: ALL 64 u64 loads in one flight, one fold-check ----
    const unsigned int* hpar = hbuf + (long)((t - 1) & 1) * 65536;
    const unsigned int* hb0 = hpar + hrow;
    const unsigned int* hb1 = hb0 + 16 * 1024;
    unsigned long long hv[64];
    unsigned long long d;
    H_BURST();
    H_CHECK();
    if (!__all(d == 0ull)) {
      do {
        __builtin_amdgcn_s_sleep(2);   // back off; avoid L3 poll storm
        H_BURST();
        H_CHECK();
      } while (!__all(d == 0ull));
    }

    // ---- h-side K from LDS weights ----
#pragma unroll
    for (int kk = 0; kk < 8; ++kk) {
      bf16x8 wb[4];
      const int el = wv * 256 + ((kk * 32 + q * 8) ^ rs);
#pragma unroll
      for (int nt = 0; nt < 4; ++nt)
        wb[nt] = *(const bf16x8*)&whl[(nt * 16 + r) * 1024 + el];
      bf16x8 a0 = unpack4(&hv[kk * 4]);
      bf16x8 a1 = unpack4(&hv[32 + kk * 4]);
#pragma unroll
      for (int nt = 0; nt < 4; ++nt) {
        acc[0][nt] = __builtin_amdgcn_mfma_f32_16x16x32_bf16(a0, wb[nt], acc[0][nt], 0, 0, 0);
        acc[1][nt] = __builtin_amdgcn_mfma_f32_16x16x32_bf16(a1, wb[nt], acc[1][nt], 0, 0, 0);
      }
    }

    // ---- cross-wave K reduction (sync1: drains only old stores -> cheap) ----
#pragma unroll
    for (int mt = 0; mt < 2; ++mt)
#pragma unroll
      for (int nt = 0; nt < 4; ++nt)
        *(floatx4*)(&pc[wv][mt * 4 + nt][lane][0]) = acc[mt][nt];
    __syncthreads();

    // ---- gates + state update ----
    float hvv[2];
#pragma unroll
    for (int e = 0; e < 2; ++e) {
      float gs[4];
#pragma unroll
      for (int gt = 0; gt < 4; ++gt)
        gs[gt] = bs[gt] + pc[0][e * 4 + gt][lidx][rg] + pc[1][e * 4 + gt][lidx][rg] +
                 pc[2][e * 4 + gt][lidx][rg] + pc[3][e * 4 + gt][lidx][rg];
      const float f = fsig(gs[0]), ii = fsig(gs[1]), o = fsig(gs[2]);
      const float cd = ftanh(gs[3]);
      cst[e] = f * cst[e] + ii * cd;
      hvv[e] = o * ftanh(cst[e]);
    }

    // sync2 BEFORE publish: pc reads complete (nothing to drain), and all
    // waves' h-reads are ordered before any wave's publish (protocol req).
    __syncthreads();

    // ---- publish tagged h_t (UC stores fly under next step's compute) ----
    const unsigned int tagw = (unsigned int)(t + 1);
#pragma unroll
    for (int e = 0; e < 2; ++e) {
      unsigned short hb16 = f2bf(hvv[e]);
      unsigned short nbv = (unsigned short)__shfl_xor((int)hb16, 1, 64);
      if ((ej & 1) == 0) {
        unsigned long long pv =
            ((unsigned long long)((((unsigned int)hb16) << 16) | tagw)) |
            (((unsigned long long)((((unsigned int)nbv) << 16) | tagw)) << 32);
        unsigned long long* hp = (unsigned long long*)(hbuf + (long)(t & 1) * 65536 +
            (long)(g * 32 + e * 16 + eb) * 1024 + s * 16 + ej);
        __hip_atomic_store(hp, pv, __ATOMIC_RELAXED, __HIP_MEMORY_SCOPE_AGENT);
      }
      // h_seq / finals: normal cached stores (write-back; flushed at end)
      const long ob = (long)(g * 32 + e * 16 + eb) * 1024 + s * 16 + ej;
      out[(long)t * 65536 + ob] = hvv[e];
      if (t == 511) {
        out[33554432l + ob] = hvv[e];
        out[33619968l + ob] = cst[e];
      }
    }
  }
}

extern "C" void kernel_launch(void* const* d_in, const int* in_sizes, int n_in,
                              void* d_out, int out_size, void* d_ws, size_t ws_size,
                              hipStream_t stream) {
  (void)in_sizes; (void)n_in; (void)out_size; (void)ws_size;
  KPtrs P;
  for (int i = 0; i < 17; ++i) P.p[i] = (const float*)d_in[i];
  pack_kernel<<<dim3(2048), dim3(256), 0, stream>>>(P, (unsigned char*)d_ws);
  lstm_kernel<<<dim3(128), dim3(256), 0, stream>>>((const unsigned char*)d_ws, (float*)d_out);
}

// Round 6
// 3955.857 us; speedup vs baseline: 1.4832x; 1.4832x over previous
//
#include <hip/hip_runtime.h>

// ---------------- problem constants ----------------
// S=512 seq, B=64 batch, I=256 in, H=1024 hidden, 4H=4096 gates
// Wx = [W1 W3 W5 W7] (input side), Wh = [W2 W4 W6 W8] (hidden side)
// out: h_seq (512,64,1024) fp32, then h_final (64,1024), c_final (64,1024)

// ---------------- workspace layout (bytes) ----------------
#define OFF_XB    0ul          // bf16 x      [512][64][256]   = 16 MiB
#define OFF_WXP   16777216ul   // bf16 Wx^T   [4096][256]      =  2 MiB (packed [col][k])
#define OFF_WHP   18874368ul   // bf16 Wh^T   [4096][1024]     =  8 MiB (packed [col][k], PRE-SWIZZLED)
#define OFF_BIAS  27262976ul   // f32 bx+bh   [4096]
#define OFF_HBUF  27279360ul   // bf16 h      [2][64][1024]    = 256 KiB double buffer
#define OFF_CNR   27541504ul   // int canary  [2][64][4] = 512 ints (per producer WAVE)

typedef __attribute__((ext_vector_type(8))) __bf16 bf16x8;
typedef __attribute__((ext_vector_type(4))) float  floatx4;

struct KPtrs { const float* p[17]; };

__device__ __forceinline__ unsigned short f2bf(float f) {  // fp32 -> bf16 RTN-even
  unsigned int u = __float_as_uint(f);
  u += 0x7fffu + ((u >> 16) & 1u);
  return (unsigned short)(u >> 16);
}

__device__ __forceinline__ bf16x8 ld16(const unsigned short* p) {
  return *(const bf16x8*)p;   // cached global_load_dwordx4
}

// L3-coherent (agent-scope, L2-bypassing) 16B load as 2x relaxed u64 atomics
__device__ __forceinline__ bf16x8 ldsys16(const unsigned short* p) {
  unsigned long long a =
      __hip_atomic_load((const unsigned long long*)p,       __ATOMIC_RELAXED, __HIP_MEMORY_SCOPE_AGENT);
  unsigned long long b =
      __hip_atomic_load((const unsigned long long*)(p + 4), __ATOMIC_RELAXED, __HIP_MEMORY_SCOPE_AGENT);
  unsigned long long arr[2] = {a, b};
  bf16x8 r;
  __builtin_memcpy(&r, arr, 16);
  return r;
}

__device__ __forceinline__ int lduc32(const int* p) {
  return __hip_atomic_load(p, __ATOMIC_RELAXED, __HIP_MEMORY_SCOPE_AGENT);
}

__device__ __forceinline__ float fsig(float x) {
  return __builtin_amdgcn_rcpf(1.f + __expf(-x));
}
__device__ __forceinline__ float ftanh(float x) {
  return 1.f - 2.f * __builtin_amdgcn_rcpf(1.f + __expf(2.f * x));
}

// ---------------- pack/convert + state init ----------------
__global__ void pack_kernel(KPtrs P, unsigned char* ws) {
  unsigned short* xb   = (unsigned short*)(ws + OFF_XB);
  unsigned short* wxp  = (unsigned short*)(ws + OFF_WXP);
  unsigned short* whp  = (unsigned short*)(ws + OFF_WHP);
  float*          bias = (float*)(ws + OFF_BIAS);
  unsigned int*   hb32 = (unsigned int*)(ws + OFF_HBUF);
  int*            cnr  = (int*)(ws + OFF_CNR);
  const float* x = P.p[0];

  const long tid = (long)blockIdx.x * blockDim.x + threadIdx.x;
  const long nth = (long)gridDim.x * blockDim.x;

  for (long e = tid; e < 8388608l; e += nth)       // x -> bf16, same flat layout
    xb[e] = f2bf(x[e]);
  for (long e = tid; e < 1048576l; e += nth) {     // Wx packed [col][k]
    int c = (int)(e >> 8), i = (int)(e & 255);
    int gg = c >> 10, j = c & 1023;
    wxp[e] = f2bf(P.p[1 + 4 * gg][i * 1024 + j]);  // W1,W3,W5,W7
  }
  // Wh packed [col][k], PRE-SWIZZLED: element (c,k) stored at k ^ ((c&7)<<3)
  // so LDS staging is a plain linear copy and ds_read_b128 with the same XOR
  // on the read side is bank-balanced. (Verified correct in R3/R4/R5.)
  for (long e = tid; e < 4194304l; e += nth) {
    int c = (int)(e >> 10), k = (int)(e & 1023);
    int gg = c >> 10, j = c & 1023;
    long dst = ((long)c << 10) | (long)(k ^ ((c & 7) << 3));
    whp[dst] = f2bf(P.p[3 + 4 * gg][k * 1024 + j]);  // W2,W4,W6,W8
  }
  for (long e = tid; e < 4096l; e += nth) {        // bx + bh
    int gg = (int)(e >> 10), j = (int)(e & 1023);
    bias[e] = P.p[2 + 4 * gg][j] + P.p[4 + 4 * gg][j];
  }
  // h double buffer = 0 (UC stores: land at the L3 coherence point)
  for (long e = tid; e < 65536l; e += nth)
    __hip_atomic_store(&hb32[e], 0u, __ATOMIC_RELAXED, __HIP_MEMORY_SCOPE_AGENT);
  // canaries = -1  (h_{-1} ready)
  for (long e = tid; e < 512l; e += nth)
    __hip_atomic_store(&cnr[e], -1, __ATOMIC_RELAXED, __HIP_MEMORY_SCOPE_AGENT);
}

// ---------------- persistent fused LSTM ----------------
// 128 blocks (proven co-resident) = 2 batch-groups (32 batches) x 64
// hidden-slices (16 units x 4 gates), 4 waves K-split.
//
// Detection and data are SPLIT (R5 lesson: a tagged 128-VGPR burst cannot be
// kept resident; re-bursting on miss doubles traffic):
//  - canary[g][s][wave] = t, stored by each producer WAVE after its OWN
//    s_waitcnt vmcnt(0) (no block barrier, no out-store drain, no flag hop).
//  - consumer wave polls exactly the 64 canaries of the 16 producer blocks in
//    its K-range (1 u32/lane, issued early, checked after x-MFMAs).
//  - h data is UNTAGGED bf16: 32 u64/thread (64 VGPR - fits), issued ONCE
//    after detection, pinned by sched_barrier(0) -> single L3 round trip.
//    Never re-issued: the canary already certified freshness.
// Safety (overwrite-while-read impossible): my publish of h_t (parity t&1,
// overwriting h_{t-2}) happens only after I verified canary==t-1 from every
// producer wave in my K-range; each such wave published h_{t-1} only after
// its own h_{t-2} reads completed (publish value is data-dependent on them),
// and block barriers order all intra-block waves' reads before the next
// step's publish. Applies symmetrically to every reader of h_{t-2}.
// Barriers: exactly 2 per step, both at drain-nothing positions (R4 lesson:
// a store-draining barrier costs ~900 cy).
__global__ void __launch_bounds__(256, 1)
lstm_kernel(const unsigned char* __restrict__ ws, float* __restrict__ out) {
  const unsigned short* xb   = (const unsigned short*)(ws + OFF_XB);
  const unsigned short* wxp  = (const unsigned short*)(ws + OFF_WXP);
  const unsigned short* whp  = (const unsigned short*)(ws + OFF_WHP);
  const float*          bias = (const float*)(ws + OFF_BIAS);
  unsigned short*       hbuf = (unsigned short*)(ws + OFF_HBUF);
  int*                  cnr  = (int*)(ws + OFF_CNR);

  const int tid = threadIdx.x;
  const int wv = tid >> 6, lane = tid & 63;
  const int r = lane & 15, q = lane >> 4;          // MFMA frag row + k-quad
  const int s = blockIdx.x & 63, g = blockIdx.x >> 6;

  __shared__ unsigned short whl[65536];            // 128 KiB swizzled Wh slice
  __shared__ float pc[4][8][64][4];                // 32 KiB cross-wave reduce
                                                   // total 160 KiB (CU max)

  // ---- stage Wh slice into LDS (linear copy; swizzle pre-baked in whp) ----
  for (int ch = tid; ch < 8192; ch += 256) {
    const int le = ch * 8;                         // bf16 element index in whl
    const int rl = le >> 10, k8 = le & 1023;       // local row 0..63
    const int cg = (rl >> 4) * 1024 + s * 16 + (rl & 15);   // global gate col
    *(bf16x8*)&whl[le] = ld16(whp + (long)cg * 1024 + k8);
  }

  // ---- Wx fragments in registers (loop-invariant, 32 VGPR) ----
  bf16x8 wxf[4][2];
#pragma unroll
  for (int nt = 0; nt < 4; ++nt) {
    const int c = nt * 1024 + s * 16 + r;
#pragma unroll
    for (int kk = 0; kk < 2; ++kk)
      wxf[nt][kk] = ld16(wxp + (long)c * 256 + wv * 64 + kk * 32 + q * 8);
  }

  // epilogue mapping: thread -> (batches eb, eb+16 ; hidden col ej)
  const int ej = tid & 15, eb = tid >> 4;
  const int lidx = ej | ((eb >> 2) << 4), rg = eb & 3;   // C-frag coords
  float bs[4];
#pragma unroll
  for (int gt = 0; gt < 4; ++gt) bs[gt] = bias[gt * 1024 + s * 16 + ej];

  const unsigned short* xa0 = xb + (long)(g * 32 + r) * 256 + q * 8;
  const int rs = (r & 7) << 3;                     // LDS XOR swizzle term
  // consumer wave wv reads k in [wv*256, wv*256+256) -> producers
  // s' in [wv*16, wv*16+16), all 4 publisher waves: one canary per lane.
  const int cidx = g * 256 + (wv * 16 + (lane >> 2)) * 4 + (lane & 3);
  const int pidx = g * 256 + s * 4 + wv;           // my producer canary

  float cst[2] = {0.f, 0.f};
  __syncthreads();                                 // whl staged

  for (int t = 0; t < 512; ++t) {
    // ---- canary load first (oldest in flight; latency hides under x) ----
    int cv = lduc32(&cnr[cidx]);

    // ---- x loads + x-side K (independent of peers) ----
    const unsigned short* xaT = xa0 + (long)t * 16384;
    bf16x8 xv[2][2];
#pragma unroll
    for (int kk = 0; kk < 2; ++kk) {
      xv[0][kk] = ld16(xaT + wv * 64 + kk * 32);
      xv[1][kk] = ld16(xaT + 16 * 256 + wv * 64 + kk * 32);
    }

    floatx4 acc[2][4];
#pragma unroll
    for (int mt = 0; mt < 2; ++mt)
#pragma unroll
      for (int nt = 0; nt < 4; ++nt) acc[mt][nt] = (floatx4){0.f, 0.f, 0.f, 0.f};

#pragma unroll
    for (int kk = 0; kk < 2; ++kk)
#pragma unroll
      for (int nt = 0; nt < 4; ++nt) {
        acc[0][nt] = __builtin_amdgcn_mfma_f32_16x16x32_bf16(xv[0][kk], wxf[nt][kk], acc[0][nt], 0, 0, 0);
        acc[1][nt] = __builtin_amdgcn_mfma_f32_16x16x32_bf16(xv[1][kk], wxf[nt][kk], acc[1][nt], 0, 0, 0);
      }

    // ---- detection: this wave's 64 producer-wave canaries >= t-1 ----
    const int need = t - 1;
    while (!__all(cv >= need))
      cv = lduc32(&cnr[cidx]);
    asm volatile("" ::: "memory");   // no h load may hoist above the gate

    // ---- h burst: 32 u64/thread, ALL issued before any MFMA wait ----
    const unsigned short* ha =
        hbuf + (long)((t - 1) & 1) * 65536 + ((long)g * 32 + r) * 1024 + q * 8;
    bf16x8 hv0[8], hv1[8];
#pragma unroll
    for (int kk = 0; kk < 8; ++kk) {
      const int k0 = wv * 256 + kk * 32;
      hv0[kk] = ldsys16(ha + k0);
      hv1[kk] = ldsys16(ha + 16 * 1024 + k0);
    }
    __builtin_amdgcn_sched_barrier(0);   // pin issue order: loads before MFMAs

    // ---- h-side K from LDS weights ----
#pragma unroll
    for (int kk = 0; kk < 8; ++kk) {
      bf16x8 wb[4];
      const int el = wv * 256 + ((kk * 32 + q * 8) ^ rs);
#pragma unroll
      for (int nt = 0; nt < 4; ++nt)
        wb[nt] = *(const bf16x8*)&whl[(nt * 16 + r) * 1024 + el];
#pragma unroll
      for (int nt = 0; nt < 4; ++nt) {
        acc[0][nt] = __builtin_amdgcn_mfma_f32_16x16x32_bf16(hv0[kk], wb[nt], acc[0][nt], 0, 0, 0);
        acc[1][nt] = __builtin_amdgcn_mfma_f32_16x16x32_bf16(hv1[kk], wb[nt], acc[1][nt], 0, 0, 0);
      }
    }

    // ---- cross-wave K reduction (sync1: nothing young in flight, cheap) ----
#pragma unroll
    for (int mt = 0; mt < 2; ++mt)
#pragma unroll
      for (int nt = 0; nt < 4; ++nt)
        *(floatx4*)(&pc[wv][mt * 4 + nt][lane][0]) = acc[mt][nt];
    __syncthreads();

    // ---- gates + state update ----
    float hvv[2];
#pragma unroll
    for (int e = 0; e < 2; ++e) {
      float gs[4];
#pragma unroll
      for (int gt = 0; gt < 4; ++gt)
        gs[gt] = bs[gt] + pc[0][e * 4 + gt][lidx][rg] + pc[1][e * 4 + gt][lidx][rg] +
                 pc[2][e * 4 + gt][lidx][rg] + pc[3][e * 4 + gt][lidx][rg];
      const float f = fsig(gs[0]), ii = fsig(gs[1]), o = fsig(gs[2]);
      const float cd = ftanh(gs[3]);
      cst[e] = f * cst[e] + ii * cd;
      hvv[e] = o * ftanh(cst[e]);
    }

    // sync2: pc reads complete before next step's pc writes; nothing issued
    // since sync1 -> drains nothing.
    __syncthreads();

    // ---- publish h_t (UC stores), per-wave ack, per-wave canary ----
#pragma unroll
    for (int e = 0; e < 2; ++e) {
      unsigned short hb16 = f2bf(hvv[e]);
      unsigned short nbv = (unsigned short)__shfl_xor((int)hb16, 1, 64);
      if ((ej & 1) == 0) {
        unsigned int pv = (unsigned int)hb16 | ((unsigned int)nbv << 16);
        unsigned int* hp = (unsigned int*)(hbuf + (long)(t & 1) * 65536 +
            (long)(g * 32 + e * 16 + eb) * 1024 + s * 16 + ej);
        __hip_atomic_store(hp, pv, __ATOMIC_RELAXED, __HIP_MEMORY_SCOPE_AGENT);
      }
    }
    // per-wave: wait ONLY this wave's stores acked at L3, then canary.
    asm volatile("s_waitcnt vmcnt(0)" ::: "memory");
    if (lane == 0)
      __hip_atomic_store(&cnr[pidx], t, __ATOMIC_RELAXED, __HIP_MEMORY_SCOPE_AGENT);

    // ---- h_seq / finals: cached stores, issued AFTER the canary so they
    // never sit in front of the next publish ack ----
#pragma unroll
    for (int e = 0; e < 2; ++e) {
      const long ob = (long)(g * 32 + e * 16 + eb) * 1024 + s * 16 + ej;
      out[(long)t * 65536 + ob] = hvv[e];
      if (t == 511) {
        out[33554432l + ob] = hvv[e];
        out[33619968l + ob] = cst[e];
      }
    }
  }
}

extern "C" void kernel_launch(void* const* d_in, const int* in_sizes, int n_in,
                              void* d_out, int out_size, void* d_ws, size_t ws_size,
                              hipStream_t stream) {
  (void)in_sizes; (void)n_in; (void)out_size; (void)ws_size;
  KPtrs P;
  for (int i = 0; i < 17; ++i) P.p[i] = (const float*)d_in[i];
  pack_kernel<<<dim3(2048), dim3(256), 0, stream>>>(P, (unsigned char*)d_ws);
  lstm_kernel<<<dim3(128), dim3(256), 0, stream>>>((const unsigned char*)d_ws, (float*)d_out);
}